// Round 1
// baseline (2309.052 us; speedup 1.0000x reference)
//
#include <hip/hip_runtime.h>

typedef float f32x4 __attribute__((ext_vector_type(4)));
typedef __bf16 bf16x8 __attribute__((ext_vector_type(8)));
typedef unsigned short u16;
typedef unsigned int u32;

#define VOCAB 50257
#define KDIM 1024
#define MROWS 2048
#define TSEQ 256
#define LOGN ((size_t)MROWS * VOCAB)

__device__ __forceinline__ u16 f2bf(float f) {
    u32 u = __builtin_bit_cast(u32, f);
    u = (u + 0x7FFFu + ((u >> 16) & 1u)) >> 16;
    return (u16)u;
}

__device__ __forceinline__ float sigm(float x) { return 1.0f / (1.0f + __expf(-x)); }

// ---------------- conversions / small prep ----------------

__global__ void conv_bf16(const float4* __restrict__ in, ushort4* __restrict__ out, long n4) {
    long i = (long)blockIdx.x * blockDim.x + threadIdx.x;
    long stride = (long)gridDim.x * blockDim.x;
    for (; i < n4; i += stride) {
        float4 v = in[i];
        ushort4 o;
        o.x = f2bf(v.x); o.y = f2bf(v.y); o.z = f2bf(v.z); o.w = f2bf(v.w);
        out[i] = o;
    }
}

__global__ void bias_sum(const float* __restrict__ a, const float* __restrict__ b,
                         float* __restrict__ o) {
    int i = blockIdx.x * 256 + threadIdx.x;
    if (i < 4096) o[i] = a[i] + b[i];
}

__global__ __launch_bounds__(256) void gather_emb(const int* __restrict__ x,
                                                  const float* __restrict__ embW,
                                                  u16* __restrict__ out) {
    int m = blockIdx.x;                       // 0..2047 = b*256+t
    int row = x[m];
    const float4* src = (const float4*)(embW + (size_t)row * KDIM);
    ushort4* dst = (ushort4*)(out + (size_t)m * KDIM);
    float4 v = src[threadIdx.x];
    ushort4 o;
    o.x = f2bf(v.x); o.y = f2bf(v.y); o.z = f2bf(v.z); o.w = f2bf(v.w);
    dst[threadIdx.x] = o;
}

// ---------------- bf16 MFMA GEMM (C = A * B^T + bias), A[M][K], B[Nb][K] ----------------

#define BM 128
#define BN 128
#define BKT 32

__device__ __forceinline__ void gl_lds16(const u16* g, const u16* l) {
    __builtin_amdgcn_global_load_lds(
        (const __attribute__((address_space(1))) u32*)g,
        (__attribute__((address_space(3))) u32*)l, 16, 0, 0);
}

__device__ __forceinline__ int swz(int r) { return (r & 3) ^ ((r >> 2) & 3); }

__global__ __launch_bounds__(256, 2)
void gemm_bt(const u16* __restrict__ A, const u16* __restrict__ Bm,
             const float* __restrict__ bias, float* __restrict__ C,
             int N, int Nb, int K, int ldc)
{
    __shared__ __align__(16) u16 As[BM * BKT];   // 8 KB
    __shared__ __align__(16) u16 Bs[BN * BKT];   // 8 KB
    const int tid  = threadIdx.x;
    const int lane = tid & 63;
    const int wid  = tid >> 6;
    const int bm = blockIdx.y, bn = blockIdx.x;
    const int wr = wid >> 1, wc = wid & 1;       // 2x2 waves, 64x64 each

    // staging: idx = half*256 + tid covers 512 (row,slot16B) pairs per array
    const int rr0 = tid >> 2, ss0 = tid & 3;
    const int rr1 = rr0 + 64;
    const int sg0 = ss0 ^ swz(rr0);
    const int sg1 = ss0 ^ swz(rr1);

    const u16* a0 = A + (size_t)(bm * BM + rr0) * K + sg0 * 8;
    const u16* a1 = A + (size_t)(bm * BM + rr1) * K + sg1 * 8;
    int br0 = bn * BN + rr0; br0 = br0 < Nb ? br0 : Nb - 1;   // clamp OOB rows
    int br1 = bn * BN + rr1; br1 = br1 < Nb ? br1 : Nb - 1;
    const u16* b0 = Bm + (size_t)br0 * K + sg0 * 8;
    const u16* b1 = Bm + (size_t)br1 * K + sg1 * 8;

    const u16* aLds0 = As + wid * 512;           // wave-uniform LDS bases
    const u16* aLds1 = As + 2048 + wid * 512;
    const u16* bLds0 = Bs + wid * 512;
    const u16* bLds1 = Bs + 2048 + wid * 512;

    // fragment LDS element offsets (swizzled read side)
    const int lrow = lane & 15, ksl = lane >> 4;
    int aoff[4], boff[4];
#pragma unroll
    for (int i = 0; i < 4; ++i) {
        int ar = wr * 64 + i * 16 + lrow;
        aoff[i] = ar * 32 + (ksl ^ swz(ar)) * 8;
        int brr = wc * 64 + i * 16 + lrow;
        boff[i] = brr * 32 + (ksl ^ swz(brr)) * 8;
    }

    f32x4 acc[4][4] = {};
    const int KT = K / BKT;
    for (int kt = 0; kt < KT; ++kt) {
        const int ke = kt * BKT;
        gl_lds16(a0 + ke, aLds0);
        gl_lds16(a1 + ke, aLds1);
        gl_lds16(b0 + ke, bLds0);
        gl_lds16(b1 + ke, bLds1);
        __syncthreads();
        bf16x8 af[4], bfb[4];
#pragma unroll
        for (int i = 0; i < 4; ++i) af[i] = *(const bf16x8*)(As + aoff[i]);
#pragma unroll
        for (int i = 0; i < 4; ++i) bfb[i] = *(const bf16x8*)(Bs + boff[i]);
#pragma unroll
        for (int mi = 0; mi < 4; ++mi)
#pragma unroll
            for (int ni = 0; ni < 4; ++ni)
                acc[mi][ni] = __builtin_amdgcn_mfma_f32_16x16x32_bf16(
                    af[mi], bfb[ni], acc[mi][ni], 0, 0, 0);
        __syncthreads();
    }

    // C/D layout: col = lane&15, row = (lane>>4)*4 + reg
    const int crl = lane >> 4, ccl = lane & 15;
    const int row0 = bm * BM + wr * 64, col0 = bn * BN + wc * 64;
#pragma unroll
    for (int ni = 0; ni < 4; ++ni) {
        int col = col0 + ni * 16 + ccl;
        if (col < N) {
            float bv = bias[col];
#pragma unroll
            for (int mi = 0; mi < 4; ++mi) {
                int row = row0 + mi * 16 + crl * 4;
                float* cp = C + (size_t)row * ldc + col;
#pragma unroll
                for (int r = 0; r < 4; ++r)
                    cp[(size_t)r * ldc] = acc[mi][ni][r] + bv;
            }
        }
    }
}

// ---------------- LSTM step: one wave per block, block owns 4 h-columns ----------------
// D[16 batch(pad)][16 rows] = h_bf16[16][1024] * Whh_rows^T via 32 MFMAs.
// Block b owns gate rows {q*1024 + 4b + jj} for q=0..3, jj=0..3 (wrow = q*4+jj).

__global__ __launch_bounds__(64)
void lstm_step(const u16* __restrict__ Whh,   // [4096][1024] bf16
               const u16* __restrict__ hin,   // [16][1024] bf16, rows 8..15 = 0
               u16* __restrict__ hout,        // [16][1024] bf16
               const float* __restrict__ xproj, // [2048][4096] f32 (m = b*256+t)
               float* __restrict__ c,         // [8][1024] f32
               u16* __restrict__ hall,        // [2048][1024] bf16
               float* __restrict__ hf32,      // [8][1024] f32
               int t)
{
    const int lane = threadIdx.x;
    const int wrow = lane & 15, ksl = lane >> 4;
    const int q = wrow >> 2, jj = wrow & 3;
    const int j = blockIdx.x * 4 + jj;
    const int grow = q * 1024 + j;
    const u16* bp = Whh + (size_t)grow * KDIM + ksl * 8;
    const u16* ap = hin + wrow * KDIM + ksl * 8;

    f32x4 acc0 = {}, acc1 = {};
#pragma unroll
    for (int k0 = 0; k0 < KDIM; k0 += 64) {
        bf16x8 av0 = *(const bf16x8*)(ap + k0);
        bf16x8 bv0 = *(const bf16x8*)(bp + k0);
        bf16x8 av1 = *(const bf16x8*)(ap + k0 + 32);
        bf16x8 bv1 = *(const bf16x8*)(bp + k0 + 32);
        acc0 = __builtin_amdgcn_mfma_f32_16x16x32_bf16(av0, bv0, acc0, 0, 0, 0);
        acc1 = __builtin_amdgcn_mfma_f32_16x16x32_bf16(av1, bv1, acc1, 0, 0, 0);
    }

    __shared__ float S[16][16];   // S[batch][wrow]
    if (ksl < 2) {
#pragma unroll
        for (int r = 0; r < 4; ++r) {
            int b = ksl * 4 + r;   // batch 0..7
            S[b][wrow] = (acc0[r] + acc1[r]) +
                         xproj[((size_t)b * TSEQ + t) * 4096 + grow];
        }
    }
    __syncthreads();
    if (lane < 32) {
        int b = lane >> 2, j4 = lane & 3;
        int col = blockIdx.x * 4 + j4;
        float gi = S[b][j4], gf = S[b][4 + j4], gg = S[b][8 + j4], go = S[b][12 + j4];
        float iv = sigm(gi), fv = sigm(gf), gv = tanhf(gg), ov = sigm(go);
        float cc = fv * c[b * KDIM + col] + iv * gv;
        c[b * KDIM + col] = cc;
        float hv = ov * tanhf(cc);
        u16 hb = f2bf(hv);
        hout[b * KDIM + col] = hb;
        hall[((size_t)b * TSEQ + t) * KDIM + col] = hb;
        hf32[b * KDIM + col] = hv;
    }
}

// ---------------- log_softmax over 50257, one block per row, in place ----------------

__global__ __launch_bounds__(256)
void logsoftmax_rows(float* __restrict__ out) {
    const int m = blockIdx.x;
    float* row = out + (size_t)m * VOCAB;
    const int tid = threadIdx.x;
    __shared__ float red[4];

    float mx = -1e30f;
    for (int i = tid; i < VOCAB; i += 256) mx = fmaxf(mx, row[i]);
#pragma unroll
    for (int off = 32; off > 0; off >>= 1) mx = fmaxf(mx, __shfl_xor(mx, off));
    if ((tid & 63) == 0) red[tid >> 6] = mx;
    __syncthreads();
    float MX = fmaxf(fmaxf(red[0], red[1]), fmaxf(red[2], red[3]));
    __syncthreads();

    float sm = 0.0f;
    for (int i = tid; i < VOCAB; i += 256) sm += __expf(row[i] - MX);
#pragma unroll
    for (int off = 32; off > 0; off >>= 1) sm += __shfl_xor(sm, off);
    if ((tid & 63) == 0) red[tid >> 6] = sm;
    __syncthreads();
    float lse = MX + __logf(red[0] + red[1] + red[2] + red[3]);

    for (int i = tid; i < VOCAB; i += 256) row[i] -= lse;
}

__global__ void copy_hidden(const float* __restrict__ hf, const float* __restrict__ cf,
                            float* __restrict__ out) {
    int i = blockIdx.x * 256 + threadIdx.x;
    if (i < 8192) { out[i] = hf[i]; out[8192 + i] = cf[i]; }
}

// ---------------- host ----------------

extern "C" void kernel_launch(void* const* d_in, const int* in_sizes, int n_in,
                              void* d_out, int out_size, void* d_ws, size_t ws_size,
                              hipStream_t stream)
{
    const int*   x    = (const int*)d_in[0];
    const float* embW = (const float*)d_in[1];
    const float* Wih  = (const float*)d_in[2];
    const float* Whh  = (const float*)d_in[3];
    const float* bih  = (const float*)d_in[4];
    const float* bhh  = (const float*)d_in[5];
    const float* decb = (const float*)d_in[6];
    float* out = (float*)d_out;

    char* p = (char*)d_ws;
    auto carve = [&](size_t bytes) {
        char* q = p;
        p += (bytes + 255) & ~(size_t)255;
        return q;
    };
    u16*   embW_bf = (u16*)carve((size_t)VOCAB * KDIM * 2);   // 98.2 MB
    u16*   Wih_bf  = (u16*)carve((size_t)4096 * KDIM * 2);    // 8 MB
    u16*   Whh_bf  = (u16*)carve((size_t)4096 * KDIM * 2);    // 8 MB
    u16*   emb_bf  = (u16*)carve((size_t)MROWS * KDIM * 2);   // 4 MB
    float* xproj   = (float*)carve((size_t)MROWS * 4096 * 4); // 33.6 MB
    u16*   hall_bf = (u16*)carve((size_t)MROWS * KDIM * 2);   // 4 MB
    u16*   hb0     = (u16*)carve((size_t)16 * KDIM * 2);
    u16*   hb1     = (u16*)carve((size_t)16 * KDIM * 2);
    float* cbuf    = (float*)carve((size_t)8 * KDIM * 4);
    float* hf32    = (float*)carve((size_t)8 * KDIM * 4);
    float* bsum    = (float*)carve((size_t)4096 * 4);

    hipMemsetAsync(hb0, 0, 16 * KDIM * 2, stream);
    hipMemsetAsync(hb1, 0, 16 * KDIM * 2, stream);
    hipMemsetAsync(cbuf, 0, 8 * KDIM * 4, stream);

    conv_bf16<<<1024, 256, 0, stream>>>((const float4*)Wih, (ushort4*)Wih_bf,
                                        (long)4096 * KDIM / 4);
    conv_bf16<<<1024, 256, 0, stream>>>((const float4*)Whh, (ushort4*)Whh_bf,
                                        (long)4096 * KDIM / 4);
    conv_bf16<<<2048, 256, 0, stream>>>((const float4*)embW, (ushort4*)embW_bf,
                                        (long)VOCAB * KDIM / 4);
    bias_sum<<<16, 256, 0, stream>>>(bih, bhh, bsum);
    gather_emb<<<MROWS, 256, 0, stream>>>(x, embW, emb_bf);

    // x_proj = emb * W_ih^T + (b_ih + b_hh)
    {
        dim3 g(4096 / BN, MROWS / BM);
        gemm_bt<<<g, 256, 0, stream>>>(emb_bf, Wih_bf, bsum, xproj, 4096, 4096, KDIM, 4096);
    }

    // LSTM recurrence, one launch per timestep (serial dependency)
    for (int t = 0; t < TSEQ; ++t) {
        const u16* hin = (t & 1) ? hb1 : hb0;
        u16* hout = (t & 1) ? hb0 : hb1;
        lstm_step<<<256, 64, 0, stream>>>(Whh_bf, hin, hout, xproj, cbuf, hall_bf, hf32, t);
    }

    // logits = h_all * embW^T + dec_b  (written straight into d_out)
    {
        dim3 g((VOCAB + BN - 1) / BN, MROWS / BM);
        gemm_bt<<<g, 256, 0, stream>>>(hall_bf, embW_bf, decb, out, VOCAB, VOCAB, KDIM, VOCAB);
    }

    logsoftmax_rows<<<MROWS, 256, 0, stream>>>(out);

    copy_hidden<<<32, 256, 0, stream>>>(hf32, cbuf, out + LOGN);
}